// Round 15
// baseline (120.593 us; speedup 1.0000x reference)
//
#include <hip/hip_runtime.h>

// Problem constants: nframes=8, nloc=8192, nnei=128, nall=16384, ntypes=4,
// nspline=2000. rmin=0, hh=f32(0.005), rcut=6.0.
constexpr int NFRAMES = 8;
constexpr int NLOC    = 8192;
constexpr int NNEI    = 128;
constexpr int NALL    = 16384;
constexpr int NTYPES  = 4;
constexpr int NSPLINE = 2000;
constexpr int KLIVE   = 1200;   // rr<6 => uu=rr*200<1200 => live bins [0,1200)
constexpr int KBLK    = 16;     // chunks (blocks) per (frame,type) bucket

// Opaque dataflow barrier: keeps the verified f32 rounding chain intact.
#define FP_BAR(x) asm volatile("" : "+v"(x))

__global__ __launch_bounds__(256) void pack_kernel(
    const float* __restrict__ coord, const int* __restrict__ atype,
    float4* __restrict__ pack, int* __restrict__ cnts)
{
    int t = blockIdx.x * 256 + threadIdx.x;   // grid sized exactly
    if (blockIdx.x == 0 && threadIdx.x < NFRAMES * NTYPES) cnts[threadIdx.x] = 0;
    float4 v;
    v.x = coord[3 * (size_t)t + 0];
    v.y = coord[3 * (size_t)t + 1];
    v.z = coord[3 * (size_t)t + 2];
    v.w = __int_as_float(atype[t]);
    pack[t] = v;
}

// Two-level aggregation (r14 fix, ~3us): LDS histogram, 1 global atomic per
// (block,type), then scatter.
__global__ __launch_bounds__(256) void bucket_kernel(
    const int* __restrict__ atype, int* __restrict__ perm,
    int* __restrict__ cnts)
{
    __shared__ int hist[NTYPES];
    __shared__ int base[NTYPES];
    const int t = blockIdx.x * 256 + threadIdx.x;   // 0..65535
    const int f = t >> 13;                          // block-uniform (256|8192)
    const int i = t & (NLOC - 1);
    const int ty = atype[(size_t)f * NALL + i];

    if (threadIdx.x < NTYPES) hist[threadIdx.x] = 0;
    __syncthreads();
    const int my_off = atomicAdd(&hist[ty], 1);     // LDS atomic (fast)
    __syncthreads();
    if (threadIdx.x < NTYPES)
        base[threadIdx.x] = atomicAdd(&cnts[f * NTYPES + threadIdx.x],
                                      hist[threadIdx.x]);
    __syncthreads();
    perm[(size_t)(f * NTYPES + ty) * NLOC + base[ty] + my_off] = i;
}

// VERIFIED ref chain (r11, absmax 3.8e-6 — DO NOT TOUCH):
//   ss = fma(dz,dz, fma(dx,dx, dy*dy)); rr = CR sqrtf; uu = rr * f32(1/hh);
//   idx = trunc(uu); poly/sum in f64 (post-bin). Energy zero iff
//   !valid | rr>=6; live => idx in [0,1199].
__device__ __forceinline__ double nb_energy_lds(
    float4 c, bool valid, float xl, float yl, float zl,
    float rmin, float recip, const float4* __restrict__ ltab)
{
    float dx = c.x - xl;  FP_BAR(dx);
    float dy = c.y - yl;  FP_BAR(dy);
    float dz = c.z - zl;  FP_BAR(dz);
    float my = dy * dy;                    FP_BAR(my);
    float t1 = __builtin_fmaf(dx, dx, my); FP_BAR(t1);   // canonical inner
    float ss = __builtin_fmaf(dz, dz, t1); FP_BAR(ss);
    float rr = sqrtf(ss);                  FP_BAR(rr);   // CR
    float num = rr - rmin;               FP_BAR(num);    // rmin=0: num==rr
    float uu  = num * recip;             FP_BAR(uu);     // recip-mul form
    double e = 0.0;
    if (valid && rr < 6.0f) {
        int    idx = (int)uu;                // in [0,1199] here
        double t   = (double)uu - (double)idx;           // exact (Sterbenz)
        int    tj  = __float_as_int(c.w);
        float4 cf  = ltab[tj * KLIVE + idx];             // ds_read_b128
        e = (((double)cf.x * t + (double)cf.y) * t + (double)cf.z) * t
            + (double)cf.w;
    }
    return e;
}

// r15: MLP×latency model (validated on r12 AND r14: thruput = outstanding/200cyc)
// says double the in-flight gathers per lane. Each 32-lane half now handles
// TWO locs per iteration: 8 independent pack gathers issued before any use.
// 16 waves/CU × 8 = 128 outstanding → ~0.64 req/cyc → ~25us predicted.
__global__ __launch_bounds__(1024, 8) void pairtab_lds_kernel(
    const float4* __restrict__ pack,
    const float*  __restrict__ tab,       // [NTYPES][NTYPES][NSPLINE][4]
    const float*  __restrict__ tab_info,  // [rmin, hh, nspline, ntypes]
    const int*    __restrict__ nlist,     // [NFRAMES][NLOC][NNEI] int32
    const int*    __restrict__ perm,      // [32][NLOC] bucketed loc ids
    const int*    __restrict__ cnts,      // [32]
    float*        __restrict__ out)       // [NFRAMES][NLOC]
{
    __shared__ float4 ltab[NTYPES * KLIVE];   // 76800 B

    const int bucket = blockIdx.x >> 4;       // / KBLK
    const int chunk  = blockIdx.x & (KBLK - 1);
    const int f  = bucket >> 2;
    const int ti = bucket & 3;

    // stage tab[ti][tj][0..1199][:] -> ltab[tj*1200+k] (coalesced float4)
    const float4* tsrc = (const float4*)tab + (size_t)ti * (NTYPES * NSPLINE);
    for (int idx = threadIdx.x; idx < NTYPES * KLIVE; idx += 1024) {
        int tj = idx / KLIVE;
        int k  = idx - tj * KLIVE;
        ltab[idx] = tsrc[tj * NSPLINE + k];
    }
    __syncthreads();

    const float rmin = tab_info[0];
    const float hh   = tab_info[1];
    // CR f32 reciprocal via f64 + single rounding == f32 divide(1,hh) == 200.0f
    float recip = (float)(1.0 / (double)hh);  FP_BAR(recip);

    const int cnt  = cnts[bucket];
    const int lane = threadIdx.x & 63;
    const int wave = (int)(threadIdx.x >> 6); // 0..15
    const int half = lane >> 5;
    const int lih  = lane & 31;
    const size_t fb = (size_t)f * NALL;
    const int* __restrict__ permb = perm + (size_t)bucket * NLOC;
    const int* __restrict__ nlf   = nlist + (size_t)f * NLOC * NNEI;

    // each block iteration covers 64 locs: 16 waves × 2 halves × 2 locs
    for (int s0 = chunk * 64; s0 < cnt; s0 += KBLK * 64) {
        const int sA = s0 + (wave * 2 + half) * 2;
        const int sB = sA + 1;
        const bool actA = sA < cnt;           // uniform per half
        const bool actB = sB < cnt;
        const int locA = actA ? permb[sA] : 0;
        const int locB = actB ? permb[sB] : 0;

        const float4 plA = pack[fb + locA];   // half-uniform broadcast
        const float4 plB = pack[fb + locB];

        // each half's 32 lanes read both locs' neighbor ids (int4/lane)
        const int4 jA = ((const int4*)(nlf + (size_t)locA * NNEI))[lih];
        const int4 jB = ((const int4*)(nlf + (size_t)locB * NNEI))[lih];

        const int a0 = jA.x < 0 ? 0 : jA.x, a1 = jA.y < 0 ? 0 : jA.y;
        const int a2 = jA.z < 0 ? 0 : jA.z, a3 = jA.w < 0 ? 0 : jA.w;
        const int b0 = jB.x < 0 ? 0 : jB.x, b1 = jB.y < 0 ? 0 : jB.y;
        const int b2 = jB.z < 0 ? 0 : jB.z, b3 = jB.w < 0 ? 0 : jB.w;

        // all 8 scattered gathers issued before any consumption (MLP)
        const float4 cA0 = pack[fb + a0];
        const float4 cA1 = pack[fb + a1];
        const float4 cA2 = pack[fb + a2];
        const float4 cA3 = pack[fb + a3];
        const float4 cB0 = pack[fb + b0];
        const float4 cB1 = pack[fb + b1];
        const float4 cB2 = pack[fb + b2];
        const float4 cB3 = pack[fb + b3];

        double eA = nb_energy_lds(cA0, jA.x >= 0, plA.x, plA.y, plA.z, rmin, recip, ltab)
                  + nb_energy_lds(cA1, jA.y >= 0, plA.x, plA.y, plA.z, rmin, recip, ltab)
                  + nb_energy_lds(cA2, jA.z >= 0, plA.x, plA.y, plA.z, rmin, recip, ltab)
                  + nb_energy_lds(cA3, jA.w >= 0, plA.x, plA.y, plA.z, rmin, recip, ltab);
        double eB = nb_energy_lds(cB0, jB.x >= 0, plB.x, plB.y, plB.z, rmin, recip, ltab)
                  + nb_energy_lds(cB1, jB.y >= 0, plB.x, plB.y, plB.z, rmin, recip, ltab)
                  + nb_energy_lds(cB2, jB.z >= 0, plB.x, plB.y, plB.z, rmin, recip, ltab)
                  + nb_energy_lds(cB3, jB.w >= 0, plB.x, plB.y, plB.z, rmin, recip, ltab);

        // butterfly within each 32-lane half (both accumulators)
#pragma unroll
        for (int off = 16; off >= 1; off >>= 1) {
            eA += __shfl_xor(eA, off, 64);
            eB += __shfl_xor(eB, off, 64);
        }

        if (lih == 0) {
            if (actA) out[(size_t)f * NLOC + locA] = (float)(0.5 * eA);
            if (actB) out[(size_t)f * NLOC + locB] = (float)(0.5 * eB);
        }
    }
}

// -------- r12 fallback (used only if ws_size is too small) --------
__device__ __forceinline__ double nb_energy_g(
    float4 c, bool valid, float xl, float yl, float zl,
    float rmin, float recip, const float* __restrict__ tabi)
{
    float dx = c.x - xl;  FP_BAR(dx);
    float dy = c.y - yl;  FP_BAR(dy);
    float dz = c.z - zl;  FP_BAR(dz);
    float my = dy * dy;                    FP_BAR(my);
    float t1 = __builtin_fmaf(dx, dx, my); FP_BAR(t1);
    float ss = __builtin_fmaf(dz, dz, t1); FP_BAR(ss);
    float rr = sqrtf(ss);                  FP_BAR(rr);
    float num = rr - rmin;               FP_BAR(num);
    float uu  = num * recip;             FP_BAR(uu);
    int   idx = (int)uu;
    double t  = (double)uu - (double)idx;
    int clip  = idx < 0 ? 0 : (idx > NSPLINE - 1 ? NSPLINE - 1 : idx);
    int tj    = __float_as_int(c.w);
    const float4 coef =
        *(const float4*)(tabi + (((size_t)tj * NSPLINE + clip) << 2));
    double e = (((double)coef.x * t + (double)coef.y) * t + (double)coef.z) * t
               + (double)coef.w;
    bool zero = (!valid) | (idx > NSPLINE) | (rr >= 6.0f);
    return zero ? 0.0 : e;
}

__global__ __launch_bounds__(256) void pairtab_kernel(
    const float4* __restrict__ pack, const float* __restrict__ tab,
    const float* __restrict__ tab_info, const int* __restrict__ nlist,
    float* __restrict__ out)
{
    const int lane = threadIdx.x & 63;
    const int wid  = (blockIdx.x * 256 + threadIdx.x) >> 6;
    const int half = lane >> 5;
    const int gloc = 2 * wid + half;
    const int f = gloc >> 13;
    const int i = gloc & (NLOC - 1);
    const float rmin = tab_info[0];
    const float hh   = tab_info[1];
    float recip = (float)(1.0 / (double)hh);  FP_BAR(recip);
    const float4 pl = pack[(size_t)f * NALL + i];
    const float xl = pl.x, yl = pl.y, zl = pl.z;
    const int   ti = __float_as_int(pl.w);
    const float* tabi = tab + (size_t)ti * (NTYPES * NSPLINE * 4);
    const int4 jj = ((const int4*)(nlist + (size_t)wid * 256))[lane];
    const int mj0 = jj.x < 0 ? 0 : jj.x, mj1 = jj.y < 0 ? 0 : jj.y;
    const int mj2 = jj.z < 0 ? 0 : jj.z, mj3 = jj.w < 0 ? 0 : jj.w;
    const size_t fb = (size_t)f * NALL;
    const float4 c0 = pack[fb + mj0], c1 = pack[fb + mj1];
    const float4 c2 = pack[fb + mj2], c3 = pack[fb + mj3];
    double esum = nb_energy_g(c0, jj.x >= 0, xl, yl, zl, rmin, recip, tabi)
                + nb_energy_g(c1, jj.y >= 0, xl, yl, zl, rmin, recip, tabi)
                + nb_energy_g(c2, jj.z >= 0, xl, yl, zl, rmin, recip, tabi)
                + nb_energy_g(c3, jj.w >= 0, xl, yl, zl, rmin, recip, tabi);
#pragma unroll
    for (int off = 16; off >= 1; off >>= 1)
        esum += __shfl_xor(esum, off, 64);
    if ((lane & 31) == 0) out[gloc] = (float)(0.5 * esum);
}

extern "C" void kernel_launch(void* const* d_in, const int* in_sizes, int n_in,
                              void* d_out, int out_size, void* d_ws, size_t ws_size,
                              hipStream_t stream)
{
    const float* coord   = (const float*)d_in[0];   // (8,16384,3) f32
    const float* tab     = (const float*)d_in[1];   // (4,4,2000,4) f32
    const float* tabinfo = (const float*)d_in[2];   // (4,) f32
    const int*   atype   = (const int*)d_in[3];     // (8,16384) int32
    const int*   nlist   = (const int*)d_in[4];     // (8,8192,128) int32
    float* out  = (float*)d_out;                    // (8,8192,1) f32

    // ws layout: pack 2MB | perm 1MB | cnts 128B
    float4* pack = (float4*)d_ws;
    int*    perm = (int*)((char*)d_ws + 2 * 1024 * 1024);
    int*    cnts = (int*)((char*)d_ws + 3 * 1024 * 1024);
    const size_t need = 3 * 1024 * 1024 + 128;

    pack_kernel<<<(NFRAMES * NALL) / 256, 256, 0, stream>>>(coord, atype, pack,
                                                            cnts);
    if (ws_size >= need) {
        bucket_kernel<<<(NFRAMES * NLOC) / 256, 256, 0, stream>>>(atype, perm, cnts);
        pairtab_lds_kernel<<<NFRAMES * NTYPES * KBLK, 1024, 0, stream>>>(
            pack, tab, tabinfo, nlist, perm, cnts, out);
    } else {
        pairtab_kernel<<<(NFRAMES * NLOC) / 8, 256, 0, stream>>>(
            pack, tab, tabinfo, nlist, out);
    }
}

// Round 16
// 116.412 us; speedup vs baseline: 1.0359x; 1.0359x over previous
//
#include <hip/hip_runtime.h>

// Problem constants: nframes=8, nloc=8192, nnei=128, nall=16384, ntypes=4,
// nspline=2000. rmin=0, hh=f32(0.005), rcut=6.0.
constexpr int NFRAMES = 8;
constexpr int NLOC    = 8192;
constexpr int NNEI    = 128;
constexpr int NALL    = 16384;
constexpr int NTYPES  = 4;
constexpr int NSPLINE = 2000;
constexpr int KLIVE   = 1200;   // rr<6 => uu=rr*200<1200 => live bins [0,1200)
constexpr int KBLK    = 8;      // chunks per bucket: 256 blocks = 1/CU

// Opaque dataflow barrier: keeps the verified f32 rounding chain intact.
#define FP_BAR(x) asm volatile("" : "+v"(x))

__global__ __launch_bounds__(256) void pack_kernel(
    const float* __restrict__ coord, const int* __restrict__ atype,
    float4* __restrict__ pack, int* __restrict__ cnts)
{
    int t = blockIdx.x * 256 + threadIdx.x;   // grid sized exactly
    if (blockIdx.x == 0 && threadIdx.x < NFRAMES * NTYPES) cnts[threadIdx.x] = 0;
    float4 v;
    v.x = coord[3 * (size_t)t + 0];
    v.y = coord[3 * (size_t)t + 1];
    v.z = coord[3 * (size_t)t + 2];
    v.w = __int_as_float(atype[t]);
    pack[t] = v;
}

// Two-level aggregation (r14, ~3us): LDS histogram, 1 global atomic per
// (block,type), then scatter.
__global__ __launch_bounds__(256) void bucket_kernel(
    const int* __restrict__ atype, int* __restrict__ perm,
    int* __restrict__ cnts)
{
    __shared__ int hist[NTYPES];
    __shared__ int base[NTYPES];
    const int t = blockIdx.x * 256 + threadIdx.x;   // 0..65535
    const int f = t >> 13;                          // block-uniform (256|8192)
    const int i = t & (NLOC - 1);
    const int ty = atype[(size_t)f * NALL + i];

    if (threadIdx.x < NTYPES) hist[threadIdx.x] = 0;
    __syncthreads();
    const int my_off = atomicAdd(&hist[ty], 1);     // LDS atomic (fast)
    __syncthreads();
    if (threadIdx.x < NTYPES)
        base[threadIdx.x] = atomicAdd(&cnts[f * NTYPES + threadIdx.x],
                                      hist[threadIdx.x]);
    __syncthreads();
    perm[(size_t)(f * NTYPES + ty) * NLOC + base[ty] + my_off] = i;
}

// VERIFIED ref chain (r11, absmax 3.8e-6 — DO NOT TOUCH):
//   ss = fma(dz,dz, fma(dx,dx, dy*dy)); rr = CR sqrtf; uu = rr * f32(1/hh);
//   idx = trunc(uu); poly/sum in f64 (post-bin). Energy zero iff
//   !valid | rr>=6; live => idx in [0,1199].
// Invalid lanes pass c={0,0,0,0}: dx..ss are finite, valid=false skips ltab.
__device__ __forceinline__ double nb_energy_lds(
    float4 c, bool valid, float xl, float yl, float zl,
    float rmin, float recip, const float4* __restrict__ ltab)
{
    float dx = c.x - xl;  FP_BAR(dx);
    float dy = c.y - yl;  FP_BAR(dy);
    float dz = c.z - zl;  FP_BAR(dz);
    float my = dy * dy;                    FP_BAR(my);
    float t1 = __builtin_fmaf(dx, dx, my); FP_BAR(t1);   // canonical inner
    float ss = __builtin_fmaf(dz, dz, t1); FP_BAR(ss);
    float rr = sqrtf(ss);                  FP_BAR(rr);   // CR
    float num = rr - rmin;               FP_BAR(num);    // rmin=0: num==rr
    float uu  = num * recip;             FP_BAR(uu);     // recip-mul form
    double e = 0.0;
    if (valid && rr < 6.0f) {
        int    idx = (int)uu;                // in [0,1199] here
        double t   = (double)uu - (double)idx;           // exact (Sterbenz)
        int    tj  = __float_as_int(c.w);
        float4 cf  = ltab[tj * KLIVE + idx];             // ds_read_b128
        e = (((double)cf.x * t + (double)cf.y) * t + (double)cf.z) * t
            + (double)cf.w;
    }
    return e;
}

// r16 model (fits r12/r14/r15): time = scattered lane-requests x ~2.2cyc/CU
// (TA throughput ~0.45 lane-req/cyc), independent of waves & MLP. Levers:
//   (a) exec-masked gathers skip the ~20% j<0 lanes (8.4M -> 6.7M req)
//   (b) KBLK 16->8 halves table staging traffic (512->256 blocks)
__global__ __launch_bounds__(1024, 8) void pairtab_lds_kernel(
    const float4* __restrict__ pack,
    const float*  __restrict__ tab,       // [NTYPES][NTYPES][NSPLINE][4]
    const float*  __restrict__ tab_info,  // [rmin, hh, nspline, ntypes]
    const int*    __restrict__ nlist,     // [NFRAMES][NLOC][NNEI] int32
    const int*    __restrict__ perm,      // [32][NLOC] bucketed loc ids
    const int*    __restrict__ cnts,      // [32]
    float*        __restrict__ out)       // [NFRAMES][NLOC]
{
    __shared__ float4 ltab[NTYPES * KLIVE];   // 76800 B

    const int bucket = blockIdx.x >> 3;       // / KBLK
    const int chunk  = blockIdx.x & (KBLK - 1);
    const int f  = bucket >> 2;
    const int ti = bucket & 3;

    // stage tab[ti][tj][0..1199][:] -> ltab[tj*1200+k] (coalesced float4)
    const float4* tsrc = (const float4*)tab + (size_t)ti * (NTYPES * NSPLINE);
    for (int idx = threadIdx.x; idx < NTYPES * KLIVE; idx += 1024) {
        int tj = idx / KLIVE;
        int k  = idx - tj * KLIVE;
        ltab[idx] = tsrc[tj * NSPLINE + k];
    }
    __syncthreads();

    const float rmin = tab_info[0];
    const float hh   = tab_info[1];
    // CR f32 reciprocal via f64 + single rounding == f32 divide(1,hh) == 200.0f
    float recip = (float)(1.0 / (double)hh);  FP_BAR(recip);

    const int cnt  = cnts[bucket];
    const int lane = threadIdx.x & 63;
    const int wave = (int)(threadIdx.x >> 6); // 0..15
    const int half = lane >> 5;
    const int lih  = lane & 31;
    const size_t fb = (size_t)f * NALL;
    const int* __restrict__ permb = perm + (size_t)bucket * NLOC;
    const int* __restrict__ nlf   = nlist + (size_t)f * NLOC * NNEI;
    const float4 zero4 = make_float4(0.f, 0.f, 0.f, 0.f);

    // each block iteration covers 32 locs: 16 waves x 2 halves x 1 loc
    for (int s0 = chunk * 32; s0 < cnt; s0 += KBLK * 32) {
        const int s = s0 + wave * 2 + half;
        const bool active = s < cnt;          // uniform per 32-lane half
        const int loc = active ? permb[s] : 0;

        const float4 pl = pack[fb + loc];     // half-uniform broadcast
        const float xl = pl.x, yl = pl.y, zl = pl.z;

        // lanes of this half read their loc's 128 neighbor ids (int4/lane)
        const int4 jj = ((const int4*)(nlf + (size_t)loc * NNEI))[lih];

        // exec-masked gathers: invalid lanes issue NO TA request
        float4 c0 = zero4, c1 = zero4, c2 = zero4, c3 = zero4;
        if (jj.x >= 0) c0 = pack[fb + jj.x];
        if (jj.y >= 0) c1 = pack[fb + jj.y];
        if (jj.z >= 0) c2 = pack[fb + jj.z];
        if (jj.w >= 0) c3 = pack[fb + jj.w];

        double esum = nb_energy_lds(c0, jj.x >= 0, xl, yl, zl, rmin, recip, ltab)
                    + nb_energy_lds(c1, jj.y >= 0, xl, yl, zl, rmin, recip, ltab)
                    + nb_energy_lds(c2, jj.z >= 0, xl, yl, zl, rmin, recip, ltab)
                    + nb_energy_lds(c3, jj.w >= 0, xl, yl, zl, rmin, recip, ltab);

        // butterfly within each 32-lane half
#pragma unroll
        for (int off = 16; off >= 1; off >>= 1)
            esum += __shfl_xor(esum, off, 64);

        if (active && lih == 0) out[(size_t)f * NLOC + loc] = (float)(0.5 * esum);
    }
}

// -------- r12 fallback (used only if ws_size is too small) --------
__device__ __forceinline__ double nb_energy_g(
    float4 c, bool valid, float xl, float yl, float zl,
    float rmin, float recip, const float* __restrict__ tabi)
{
    float dx = c.x - xl;  FP_BAR(dx);
    float dy = c.y - yl;  FP_BAR(dy);
    float dz = c.z - zl;  FP_BAR(dz);
    float my = dy * dy;                    FP_BAR(my);
    float t1 = __builtin_fmaf(dx, dx, my); FP_BAR(t1);
    float ss = __builtin_fmaf(dz, dz, t1); FP_BAR(ss);
    float rr = sqrtf(ss);                  FP_BAR(rr);
    float num = rr - rmin;               FP_BAR(num);
    float uu  = num * recip;             FP_BAR(uu);
    int   idx = (int)uu;
    double t  = (double)uu - (double)idx;
    int clip  = idx < 0 ? 0 : (idx > NSPLINE - 1 ? NSPLINE - 1 : idx);
    int tj    = __float_as_int(c.w);
    const float4 coef =
        *(const float4*)(tabi + (((size_t)tj * NSPLINE + clip) << 2));
    double e = (((double)coef.x * t + (double)coef.y) * t + (double)coef.z) * t
               + (double)coef.w;
    bool zero = (!valid) | (idx > NSPLINE) | (rr >= 6.0f);
    return zero ? 0.0 : e;
}

__global__ __launch_bounds__(256) void pairtab_kernel(
    const float4* __restrict__ pack, const float* __restrict__ tab,
    const float* __restrict__ tab_info, const int* __restrict__ nlist,
    float* __restrict__ out)
{
    const int lane = threadIdx.x & 63;
    const int wid  = (blockIdx.x * 256 + threadIdx.x) >> 6;
    const int half = lane >> 5;
    const int gloc = 2 * wid + half;
    const int f = gloc >> 13;
    const int i = gloc & (NLOC - 1);
    const float rmin = tab_info[0];
    const float hh   = tab_info[1];
    float recip = (float)(1.0 / (double)hh);  FP_BAR(recip);
    const float4 pl = pack[(size_t)f * NALL + i];
    const float xl = pl.x, yl = pl.y, zl = pl.z;
    const int   ti = __float_as_int(pl.w);
    const float* tabi = tab + (size_t)ti * (NTYPES * NSPLINE * 4);
    const int4 jj = ((const int4*)(nlist + (size_t)wid * 256))[lane];
    const int mj0 = jj.x < 0 ? 0 : jj.x, mj1 = jj.y < 0 ? 0 : jj.y;
    const int mj2 = jj.z < 0 ? 0 : jj.z, mj3 = jj.w < 0 ? 0 : jj.w;
    const size_t fb = (size_t)f * NALL;
    const float4 c0 = pack[fb + mj0], c1 = pack[fb + mj1];
    const float4 c2 = pack[fb + mj2], c3 = pack[fb + mj3];
    double esum = nb_energy_g(c0, jj.x >= 0, xl, yl, zl, rmin, recip, tabi)
                + nb_energy_g(c1, jj.y >= 0, xl, yl, zl, rmin, recip, tabi)
                + nb_energy_g(c2, jj.z >= 0, xl, yl, zl, rmin, recip, tabi)
                + nb_energy_g(c3, jj.w >= 0, xl, yl, zl, rmin, recip, tabi);
#pragma unroll
    for (int off = 16; off >= 1; off >>= 1)
        esum += __shfl_xor(esum, off, 64);
    if ((lane & 31) == 0) out[gloc] = (float)(0.5 * esum);
}

extern "C" void kernel_launch(void* const* d_in, const int* in_sizes, int n_in,
                              void* d_out, int out_size, void* d_ws, size_t ws_size,
                              hipStream_t stream)
{
    const float* coord   = (const float*)d_in[0];   // (8,16384,3) f32
    const float* tab     = (const float*)d_in[1];   // (4,4,2000,4) f32
    const float* tabinfo = (const float*)d_in[2];   // (4,) f32
    const int*   atype   = (const int*)d_in[3];     // (8,16384) int32
    const int*   nlist   = (const int*)d_in[4];     // (8,8192,128) int32
    float* out  = (float*)d_out;                    // (8,8192,1) f32

    // ws layout: pack 2MB | perm 1MB | cnts 128B
    float4* pack = (float4*)d_ws;
    int*    perm = (int*)((char*)d_ws + 2 * 1024 * 1024);
    int*    cnts = (int*)((char*)d_ws + 3 * 1024 * 1024);
    const size_t need = 3 * 1024 * 1024 + 128;

    pack_kernel<<<(NFRAMES * NALL) / 256, 256, 0, stream>>>(coord, atype, pack,
                                                            cnts);
    if (ws_size >= need) {
        bucket_kernel<<<(NFRAMES * NLOC) / 256, 256, 0, stream>>>(atype, perm, cnts);
        pairtab_lds_kernel<<<NFRAMES * NTYPES * KBLK, 1024, 0, stream>>>(
            pack, tab, tabinfo, nlist, perm, cnts, out);
    } else {
        pairtab_kernel<<<(NFRAMES * NLOC) / 8, 256, 0, stream>>>(
            pack, tab, tabinfo, nlist, out);
    }
}